// Round 5
// baseline (569.637 us; speedup 1.0000x reference)
//
#include <hip/hip_runtime.h>
#include <stdint.h>

#define HD 8
#define DD 64
#define BSHIFT 8            // bucket covers 256 consecutive target nodes
#define BRANGE 256
#define NBMAX 512

// Native clang vector types.
typedef float  vf4 __attribute__((ext_vector_type(4)));

// Monotone float->uint mapping so unsigned atomicMax implements float max.
__device__ __forceinline__ unsigned fmap(float f) {
    unsigned u = __float_as_uint(f);
    return u ^ (unsigned)(((int)u >> 31) | 0x80000000);
}
__device__ __forceinline__ float funmap(unsigned u) {
    u ^= ((int)u < 0) ? 0x80000000u : 0xFFFFFFFFu;
    return __uint_as_float(u);
}
#define FMAP_NEG_INF 0x007FFFFFu   // maps back to -inf

// bf16 helpers. Slot layout per node (4 u32 words): word g = (bf16 h=g) | (bf16 h=g+4)<<16.
__device__ __forceinline__ unsigned pack_bf16_rne(float a, float b) {
    unsigned ua = __float_as_uint(a); ua += 0x7FFF + ((ua >> 16) & 1);
    unsigned ub = __float_as_uint(b); ub += 0x7FFF + ((ub >> 16) & 1);
    return (ua >> 16) | (ub & 0xFFFF0000u);
}
__device__ __forceinline__ float bf_lo(unsigned u) { return __uint_as_float(u << 16); }
__device__ __forceinline__ float bf_hi(unsigned u) { return __uint_as_float(u & 0xFFFF0000u); }

// Phase A: t_pk[n] = packed bf16 tanh(X[n,h,:] . W[:,h]); init m_u slots to mapped(-inf);
// zero the NB per-bucket record counters. Cacheable X loads (fill kernel proves 6.8 TB/s
// is reachable with plain cacheable traffic).
__global__ __launch_bounds__(256) void attn_tanh_kernel(
    const float* __restrict__ X, const float* __restrict__ Wk,
    unsigned* __restrict__ t_pk, uint2* __restrict__ m_init,
    unsigned* __restrict__ gcnt, int NB, int N)
{
    __shared__ float Ws[DD * HD];   // W[d*8+h], 2 KB
    int tid = threadIdx.x;
    for (int i = tid; i < DD * HD; i += 256) Ws[i] = Wk[i];

    int gid = blockIdx.x * 256 + tid;
    if (gcnt != nullptr && gid < NB) gcnt[gid] = 0;

    __syncthreads();

    int wave = tid >> 6, lane = tid & 63;
    int n0 = (blockIdx.x * 4 + wave) * 2;
    if (n0 >= N) return;
    bool two = (n0 + 1 < N);

    const vf4* Xa = (const vf4*)X + (size_t)n0 * 128;  // 512 floats/node
    vf4 z = {0.f, 0.f, 0.f, 0.f};
    vf4 xv0 = Xa[lane];
    vf4 xv1 = Xa[64 + lane];
    vf4 xv2 = two ? Xa[128 + lane] : z;
    vf4 xv3 = two ? Xa[192 + lane] : z;

    int h0 = lane >> 4, d0 = (lane & 15) << 2;
    int h1 = 4 + h0;
    float w00 = Ws[(d0 + 0) * HD + h0], w01 = Ws[(d0 + 1) * HD + h0],
          w02 = Ws[(d0 + 2) * HD + h0], w03 = Ws[(d0 + 3) * HD + h0];
    float w10 = Ws[(d0 + 0) * HD + h1], w11 = Ws[(d0 + 1) * HD + h1],
          w12 = Ws[(d0 + 2) * HD + h1], w13 = Ws[(d0 + 3) * HD + h1];

    float p0 = xv0.x * w00 + xv0.y * w01 + xv0.z * w02 + xv0.w * w03;
    float p1 = xv1.x * w10 + xv1.y * w11 + xv1.z * w12 + xv1.w * w13;
    float p2 = xv2.x * w00 + xv2.y * w01 + xv2.z * w02 + xv2.w * w03;
    float p3 = xv3.x * w10 + xv3.y * w11 + xv3.z * w12 + xv3.w * w13;

    for (int off = 8; off; off >>= 1) {
        p0 += __shfl_xor(p0, off);
        p1 += __shfl_xor(p1, off);
        p2 += __shfl_xor(p2, off);
        p3 += __shfl_xor(p3, off);
    }
    if ((lane & 15) == 0) {
        int g = lane >> 4;
        t_pk[(size_t)n0 * 4 + g] = pack_bf16_rne(tanhf(p0), tanhf(p1));
        m_init[(size_t)n0 * 4 + g] = make_uint2(FMAP_NEG_INF, FMAP_NEG_INF);
        if (two) {
            t_pk[(size_t)(n0 + 1) * 4 + g] = pack_bf16_rne(tanhf(p2), tanhf(p3));
            m_init[(size_t)(n0 + 1) * 4 + g] = make_uint2(FMAP_NEG_INF, FMAP_NEG_INF);
        }
    }
}

// Pass 1: bin edges by target bucket (tgt>>8). Per-WAVE privatized LDS histograms
// (whist[4][NB]) cut LDS atomic same-address contention 4x vs a shared table; a
// per-bucket prefix then turns each wave's row into an ABSOLUTE cursor (base comes
// from one global atomicAdd per touched bucket per block). Pass 2 writes packed 4B
// records ((tgt&255)<<SRC_BITS | src) via per-wave cursors. Overflow (cap exceeded,
// cap = mean+~45sigma) falls back to exact global atomicMax into m_u.
__global__ __launch_bounds__(256) void bin_kernel(
    const int* __restrict__ sources, const int* __restrict__ targets,
    unsigned* __restrict__ gcnt, unsigned* __restrict__ buf,
    const uint4* __restrict__ t_pk4, unsigned* __restrict__ m_u,
    int NB, int CAPB, int SRC_BITS, int E)
{
    __shared__ unsigned whist[4][NBMAX];   // 8 KB: per-wave hist, then per-wave cursor
    int tid = threadIdx.x;
    int wv  = tid >> 6;
    for (int i = tid; i < 4 * NBMAX; i += 256) ((unsigned*)whist)[i] = 0;
    __syncthreads();

    int e0 = blockIdx.x * 4096;
    #pragma unroll
    for (int k = 0; k < 16; ++k) {
        int e = e0 + k * 256 + tid;
        if (e < E) atomicAdd(&whist[wv][targets[e] >> BSHIFT], 1u);
    }
    __syncthreads();

    for (int i = tid; i < NB; i += 256) {
        unsigned h0 = whist[0][i], h1 = whist[1][i], h2 = whist[2][i], h3 = whist[3][i];
        unsigned tot = h0 + h1 + h2 + h3;
        if (tot) {
            unsigned g = atomicAdd(gcnt + i, tot);
            whist[0][i] = g;
            whist[1][i] = g + h0;
            whist[2][i] = g + h0 + h1;
            whist[3][i] = g + h0 + h1 + h2;
        }
    }
    __syncthreads();

    #pragma unroll
    for (int k = 0; k < 16; ++k) {
        int e = e0 + k * 256 + tid;
        if (e < E) {
            int tg = targets[e];            // L2/L1-hot from the count pass
            int s  = sources[e];
            int b  = tg >> BSHIFT;
            unsigned pos = atomicAdd(&whist[wv][b], 1u);   // absolute index
            if (pos < (unsigned)CAPB) {
                buf[(size_t)b * CAPB + pos] =
                    ((unsigned)(tg & (BRANGE - 1)) << SRC_BITS) | (unsigned)s;
            } else {
                uint4 tv = t_pk4[s];
                unsigned* mp = m_u + (size_t)tg * HD;
                atomicMax(mp + 0, fmap(bf_lo(tv.x)));
                atomicMax(mp + 1, fmap(bf_hi(tv.x)));
                atomicMax(mp + 2, fmap(bf_lo(tv.y)));
                atomicMax(mp + 3, fmap(bf_hi(tv.y)));
                atomicMax(mp + 4, fmap(bf_lo(tv.z)));
                atomicMax(mp + 5, fmap(bf_hi(tv.z)));
                atomicMax(mp + 6, fmap(bf_lo(tv.w)));
                atomicMax(mp + 7, fmap(bf_hi(tv.w)));
            }
        }
    }
}

// Pass 2: one block per bucket, 512 threads (2 waves/SIMD). LDS max-table with
// PADDED stride 9 (tl*9+k spreads all 32 banks; the old tl*8+k hit only 4 banks ->
// 16-way conflict on every atomic). Stream the bucket's contiguous records, gather
// t_pk4[src] (L2-resident), LDS atomicMax; then coalesced m_pk write merging m_u.
#define MTS 9
__global__ __launch_bounds__(512) void reduce_kernel(
    const unsigned* __restrict__ gcnt, const unsigned* __restrict__ buf,
    const uint4* __restrict__ t_pk4, const unsigned* __restrict__ m_u,
    uint4* __restrict__ m_pk, int CAPB, int SRC_BITS, int N)
{
    __shared__ unsigned mt[BRANGE * MTS];   // 9.2 KB
    int tid = threadIdx.x;
    int b = blockIdx.x;
    for (int i = tid; i < BRANGE * MTS; i += 512) mt[i] = FMAP_NEG_INF;
    __syncthreads();

    unsigned cnt = gcnt[b];
    if (cnt > (unsigned)CAPB) cnt = CAPB;
    unsigned srcmask = (1u << SRC_BITS) - 1;
    const unsigned* bb = buf + (size_t)b * CAPB;

    for (unsigned i = tid; i < cnt; i += 512) {
        unsigned rec = bb[i];
        unsigned s  = rec & srcmask;
        unsigned tl = rec >> SRC_BITS;
        uint4 tv = t_pk4[s];
        unsigned* mp = mt + tl * MTS;
        atomicMax(mp + 0, fmap(bf_lo(tv.x)));
        atomicMax(mp + 1, fmap(bf_hi(tv.x)));
        atomicMax(mp + 2, fmap(bf_lo(tv.y)));
        atomicMax(mp + 3, fmap(bf_hi(tv.y)));
        atomicMax(mp + 4, fmap(bf_lo(tv.z)));
        atomicMax(mp + 5, fmap(bf_hi(tv.z)));
        atomicMax(mp + 6, fmap(bf_lo(tv.w)));
        atomicMax(mp + 7, fmap(bf_hi(tv.w)));
    }
    __syncthreads();

    int n0 = b << BSHIFT;
    for (int tl = tid; tl < BRANGE; tl += 512) {
        int n = n0 + tl;
        if (n < N) {
            const unsigned* ms = mt + tl * MTS;
            const unsigned* mu = m_u + (size_t)n * HD;
            float v0 = fmaxf(funmap(ms[0]), funmap(mu[0]));
            float v1 = fmaxf(funmap(ms[1]), funmap(mu[1]));
            float v2 = fmaxf(funmap(ms[2]), funmap(mu[2]));
            float v3 = fmaxf(funmap(ms[3]), funmap(mu[3]));
            float v4 = fmaxf(funmap(ms[4]), funmap(mu[4]));
            float v5 = fmaxf(funmap(ms[5]), funmap(mu[5]));
            float v6 = fmaxf(funmap(ms[6]), funmap(mu[6]));
            float v7 = fmaxf(funmap(ms[7]), funmap(mu[7]));
            uint4 o;                       // lossless: maxes of bf16 values
            o.x = pack_bf16_rne(v0, v1);
            o.y = pack_bf16_rne(v2, v3);
            o.z = pack_bf16_rne(v4, v5);
            o.w = pack_bf16_rne(v6, v7);
            m_pk[n] = o;
        }
    }
}

// ---- Fallback path (old, proven) kernels: used only if packing/workspace fails ----

__global__ __launch_bounds__(256) void seg_max_kernel(
    const int* __restrict__ sources, const int* __restrict__ targets,
    const uint4* __restrict__ t_pk4, unsigned* __restrict__ m_u, int E)
{
    int e = blockIdx.x * 256 + threadIdx.x;
    if (e >= E) return;
    int s  = __builtin_nontemporal_load(sources + e);
    int tg = __builtin_nontemporal_load(targets + e);
    uint4 tv = t_pk4[s];
    unsigned* mp = m_u + (size_t)tg * HD;
    const uint4* m4 = (const uint4*)mp;
    uint4 c0 = m4[0];
    uint4 c1 = m4[1];
    unsigned f;
    f = fmap(bf_lo(tv.x)); if (f > c0.x) atomicMax(mp + 0, f);
    f = fmap(bf_hi(tv.x)); if (f > c0.y) atomicMax(mp + 1, f);
    f = fmap(bf_lo(tv.y)); if (f > c0.z) atomicMax(mp + 2, f);
    f = fmap(bf_hi(tv.y)); if (f > c0.w) atomicMax(mp + 3, f);
    f = fmap(bf_lo(tv.z)); if (f > c1.x) atomicMax(mp + 4, f);
    f = fmap(bf_hi(tv.z)); if (f > c1.y) atomicMax(mp + 5, f);
    f = fmap(bf_lo(tv.w)); if (f > c1.z) atomicMax(mp + 6, f);
    f = fmap(bf_hi(tv.w)); if (f > c1.w) atomicMax(mp + 7, f);
}

__global__ __launch_bounds__(256) void pack_m_kernel(
    const unsigned* __restrict__ m_u, uint4* __restrict__ m_pk, int N)
{
    int n = blockIdx.x * 256 + threadIdx.x;
    if (n >= N) return;
    const uint4* mu4 = (const uint4*)m_u + (size_t)n * 2;
    uint4 c0 = mu4[0];
    uint4 c1 = mu4[1];
    uint4 o;
    o.x = (__float_as_uint(funmap(c0.x)) >> 16) | (__float_as_uint(funmap(c0.y)) & 0xFFFF0000u);
    o.y = (__float_as_uint(funmap(c0.z)) >> 16) | (__float_as_uint(funmap(c0.w)) & 0xFFFF0000u);
    o.z = (__float_as_uint(funmap(c1.x)) >> 16) | (__float_as_uint(funmap(c1.y)) & 0xFFFF0000u);
    o.w = (__float_as_uint(funmap(c1.z)) >> 16) | (__float_as_uint(funmap(c1.w)) & 0xFFFF0000u);
    m_pk[n] = o;
}

// Phase C: out[e,h] = exp(t[src,h] - m[tgt,h]) * drop_mask[e,h].
// (Reference's s = segment_max(exp(ef-m)) + 1e-9 == 1.0f exactly in fp32.)
// 2 edges/thread: dm loads (independent) issue before the dependent t_pk/m_pk gathers,
// doubling memory-level parallelism. __expf: arg in [-2,0], error << bf16 tolerance.
// out stores NT: write-only, never reread -> skip L2 allocation.
__global__ __launch_bounds__(256) void finalize_kernel(
    const int* __restrict__ sources, const int* __restrict__ targets,
    const uint4* __restrict__ t_pk4, const uint4* __restrict__ m_pk,
    const float* __restrict__ dm, float* __restrict__ out, int E)
{
    int e0 = (blockIdx.x * 256 + threadIdx.x) * 2;
    if (e0 >= E) return;
    bool two = (e0 + 1 < E);

    int s0  = __builtin_nontemporal_load(sources + e0);
    int tg0 = __builtin_nontemporal_load(targets + e0);
    int s1  = two ? __builtin_nontemporal_load(sources + e0 + 1) : s0;
    int tg1 = two ? __builtin_nontemporal_load(targets + e0 + 1) : tg0;

    const vf4* dm4 = (const vf4*)dm;
    vf4 a0 = dm4[(size_t)e0 * 2];
    vf4 a1 = dm4[(size_t)e0 * 2 + 1];
    vf4 b0 = two ? dm4[(size_t)e0 * 2 + 2] : a0;
    vf4 b1 = two ? dm4[(size_t)e0 * 2 + 3] : a1;

    uint4 tv0 = t_pk4[s0];
    uint4 mv0 = m_pk[tg0];
    uint4 tv1 = t_pk4[s1];
    uint4 mv1 = m_pk[tg1];

    vf4 o0, o1, o2, o3;
    o0.x = __expf(bf_lo(tv0.x) - bf_lo(mv0.x)) * a0.x;
    o0.y = __expf(bf_lo(tv0.y) - bf_lo(mv0.y)) * a0.y;
    o0.z = __expf(bf_lo(tv0.z) - bf_lo(mv0.z)) * a0.z;
    o0.w = __expf(bf_lo(tv0.w) - bf_lo(mv0.w)) * a0.w;
    o1.x = __expf(bf_hi(tv0.x) - bf_hi(mv0.x)) * a1.x;
    o1.y = __expf(bf_hi(tv0.y) - bf_hi(mv0.y)) * a1.y;
    o1.z = __expf(bf_hi(tv0.z) - bf_hi(mv0.z)) * a1.z;
    o1.w = __expf(bf_hi(tv0.w) - bf_hi(mv0.w)) * a1.w;
    o2.x = __expf(bf_lo(tv1.x) - bf_lo(mv1.x)) * b0.x;
    o2.y = __expf(bf_lo(tv1.y) - bf_lo(mv1.y)) * b0.y;
    o2.z = __expf(bf_lo(tv1.z) - bf_lo(mv1.z)) * b0.z;
    o2.w = __expf(bf_lo(tv1.w) - bf_lo(mv1.w)) * b0.w;
    o3.x = __expf(bf_hi(tv1.x) - bf_hi(mv1.x)) * b1.x;
    o3.y = __expf(bf_hi(tv1.y) - bf_hi(mv1.y)) * b1.y;
    o3.z = __expf(bf_hi(tv1.z) - bf_hi(mv1.z)) * b1.z;
    o3.w = __expf(bf_hi(tv1.w) - bf_hi(mv1.w)) * b1.w;

    vf4* out4 = (vf4*)out;
    __builtin_nontemporal_store(o0, out4 + (size_t)e0 * 2);
    __builtin_nontemporal_store(o1, out4 + (size_t)e0 * 2 + 1);
    if (two) {
        __builtin_nontemporal_store(o2, out4 + (size_t)e0 * 2 + 2);
        __builtin_nontemporal_store(o3, out4 + (size_t)e0 * 2 + 3);
    }
}

extern "C" void kernel_launch(void* const* d_in, const int* in_sizes, int n_in,
                              void* d_out, int out_size, void* d_ws, size_t ws_size,
                              hipStream_t stream)
{
    const float* X       = (const float*)d_in[0];   // (B,N,H,D) fp32
    const float* Wk      = (const float*)d_in[1];   // (D,H,1)   fp32
    const int*   targets = (const int*)d_in[2];     // (B,E)
    const int*   sources = (const int*)d_in[3];     // (B,E)
    const float* dm      = (const float*)d_in[5];   // (B,E,H)

    int E = in_sizes[2];          // B=1
    int N = in_sizes[4];          // degree is (B,N)

    float* out = (float*)d_out;
    int blocksA = (N + 7) / 8;           // 4 waves/block, 2 nodes/wave
    int blocksF = (E + 511) / 512;       // finalize: 2 edges/thread

    // Binned-path parameters.
    int NB = (N + BRANGE - 1) >> BSHIFT;              // buckets of 256 nodes
    int SRC_BITS = 1;
    while ((1 << SRC_BITS) < N && SRC_BITS < 31) ++SRC_BITS;
    bool packable = (NB <= NBMAX) && (SRC_BITS + BSHIFT <= 32);
    long long capll = ((long long)(E + NB - 1) / (NB > 0 ? NB : 1));
    capll = (capll * 3) / 2;                          // mean * 1.5
    capll = (capll + 255) & ~255LL;
    int CAPB = (int)capll;

    // Workspace layout (bytes): t_pk 16N | m_u 32N | m_pk 16N | gcnt 4N | buf NB*CAPB*4
    size_t needed = (size_t)N * 68 + (size_t)NB * (size_t)CAPB * 4;

    char* w = (char*)d_ws;
    unsigned* t_pk = (unsigned*)w;
    unsigned* m_u  = (unsigned*)(w + (size_t)N * 16);
    uint4*    m_pk = (uint4*)  (w + (size_t)N * 48);

    if (packable && ws_size >= needed) {
        unsigned* gcnt = (unsigned*)(w + (size_t)N * 64);
        unsigned* buf  = (unsigned*)(w + (size_t)N * 68);

        attn_tanh_kernel<<<blocksA, 256, 0, stream>>>(X, Wk, t_pk, (uint2*)m_u, gcnt, NB, N);
        int blocksB = (E + 4095) / 4096;
        bin_kernel<<<blocksB, 256, 0, stream>>>(sources, targets, gcnt, buf,
                                                (const uint4*)t_pk, m_u, NB, CAPB, SRC_BITS, E);
        reduce_kernel<<<NB, 512, 0, stream>>>(gcnt, buf, (const uint4*)t_pk, m_u,
                                              m_pk, CAPB, SRC_BITS, N);
        finalize_kernel<<<blocksF, 256, 0, stream>>>(sources, targets, (const uint4*)t_pk,
                                                     m_pk, dm, out, E);
    } else {
        // Fallback: proven atomicMax path (identical numerics).
        attn_tanh_kernel<<<blocksA, 256, 0, stream>>>(X, Wk, t_pk, (uint2*)m_u, nullptr, 0, N);
        int blocksE = (E + 255) / 256;
        seg_max_kernel<<<blocksE, 256, 0, stream>>>(sources, targets, (const uint4*)t_pk, m_u, E);
        int blocksN = (N + 255) / 256;
        pack_m_kernel<<<blocksN, 256, 0, stream>>>(m_u, m_pk, N);
        finalize_kernel<<<blocksF, 256, 0, stream>>>(sources, targets, (const uint4*)t_pk,
                                                     m_pk, dm, out, E);
    }
}

// Round 6
// 549.191 us; speedup vs baseline: 1.0372x; 1.0372x over previous
//
#include <hip/hip_runtime.h>
#include <stdint.h>

#define HD 8
#define DD 64
#define BSHIFT 8            // bucket covers 256 consecutive target nodes
#define BRANGE 256
#define NBMAX 512

// Native clang vector types.
typedef float  vf4 __attribute__((ext_vector_type(4)));

// Monotone float->uint mapping so unsigned atomicMax implements float max.
__device__ __forceinline__ unsigned fmap(float f) {
    unsigned u = __float_as_uint(f);
    return u ^ (unsigned)(((int)u >> 31) | 0x80000000);
}
__device__ __forceinline__ float funmap(unsigned u) {
    u ^= ((int)u < 0) ? 0x80000000u : 0xFFFFFFFFu;
    return __uint_as_float(u);
}
#define FMAP_NEG_INF 0x007FFFFFu   // maps back to -inf

// bf16 helpers. Slot layout per node (4 u32 words): word g = (bf16 h=g) | (bf16 h=g+4)<<16.
__device__ __forceinline__ unsigned pack_bf16_rne(float a, float b) {
    unsigned ua = __float_as_uint(a); ua += 0x7FFF + ((ua >> 16) & 1);
    unsigned ub = __float_as_uint(b); ub += 0x7FFF + ((ub >> 16) & 1);
    return (ua >> 16) | (ub & 0xFFFF0000u);
}
__device__ __forceinline__ float bf_lo(unsigned u) { return __uint_as_float(u << 16); }
__device__ __forceinline__ float bf_hi(unsigned u) { return __uint_as_float(u & 0xFFFF0000u); }

// Phase A: t_pk[n] = packed bf16 tanh(X[n,h,:] . W[:,h]); init m_u slots to mapped(-inf);
// zero the NB per-bucket record counters. Cacheable X loads.
__global__ __launch_bounds__(256) void attn_tanh_kernel(
    const float* __restrict__ X, const float* __restrict__ Wk,
    unsigned* __restrict__ t_pk, uint2* __restrict__ m_init,
    unsigned* __restrict__ gcnt, int NB, int N)
{
    __shared__ float Ws[DD * HD];   // W[d*8+h], 2 KB
    int tid = threadIdx.x;
    for (int i = tid; i < DD * HD; i += 256) Ws[i] = Wk[i];

    int gid = blockIdx.x * 256 + tid;
    if (gcnt != nullptr && gid < NB) gcnt[gid] = 0;

    __syncthreads();

    int wave = tid >> 6, lane = tid & 63;
    int n0 = (blockIdx.x * 4 + wave) * 2;
    if (n0 >= N) return;
    bool two = (n0 + 1 < N);

    const vf4* Xa = (const vf4*)X + (size_t)n0 * 128;  // 512 floats/node
    vf4 z = {0.f, 0.f, 0.f, 0.f};
    vf4 xv0 = Xa[lane];
    vf4 xv1 = Xa[64 + lane];
    vf4 xv2 = two ? Xa[128 + lane] : z;
    vf4 xv3 = two ? Xa[192 + lane] : z;

    int h0 = lane >> 4, d0 = (lane & 15) << 2;
    int h1 = 4 + h0;
    float w00 = Ws[(d0 + 0) * HD + h0], w01 = Ws[(d0 + 1) * HD + h0],
          w02 = Ws[(d0 + 2) * HD + h0], w03 = Ws[(d0 + 3) * HD + h0];
    float w10 = Ws[(d0 + 0) * HD + h1], w11 = Ws[(d0 + 1) * HD + h1],
          w12 = Ws[(d0 + 2) * HD + h1], w13 = Ws[(d0 + 3) * HD + h1];

    float p0 = xv0.x * w00 + xv0.y * w01 + xv0.z * w02 + xv0.w * w03;
    float p1 = xv1.x * w10 + xv1.y * w11 + xv1.z * w12 + xv1.w * w13;
    float p2 = xv2.x * w00 + xv2.y * w01 + xv2.z * w02 + xv2.w * w03;
    float p3 = xv3.x * w10 + xv3.y * w11 + xv3.z * w12 + xv3.w * w13;

    for (int off = 8; off; off >>= 1) {
        p0 += __shfl_xor(p0, off);
        p1 += __shfl_xor(p1, off);
        p2 += __shfl_xor(p2, off);
        p3 += __shfl_xor(p3, off);
    }
    if ((lane & 15) == 0) {
        int g = lane >> 4;
        t_pk[(size_t)n0 * 4 + g] = pack_bf16_rne(tanhf(p0), tanhf(p1));
        m_init[(size_t)n0 * 4 + g] = make_uint2(FMAP_NEG_INF, FMAP_NEG_INF);
        if (two) {
            t_pk[(size_t)(n0 + 1) * 4 + g] = pack_bf16_rne(tanhf(p2), tanhf(p3));
            m_init[(size_t)(n0 + 1) * 4 + g] = make_uint2(FMAP_NEG_INF, FMAP_NEG_INF);
        }
    }
}

// Pass 1: bin edges by target bucket (tgt>>8). Per-wave privatized LDS histograms;
// per-bucket prefix turns each wave's row into an absolute cursor (one global
// atomicAdd per touched bucket per block). Pass 2 writes packed 4B records
// ((tgt&255)<<SRC_BITS | src). Overflow (pos >= CAPB, ~never: cap = mean+~45sigma)
// falls back to exact global atomicMax into m_u.
__global__ __launch_bounds__(256) void bin_kernel(
    const int* __restrict__ sources, const int* __restrict__ targets,
    unsigned* __restrict__ gcnt, unsigned* __restrict__ buf,
    const uint4* __restrict__ t_pk4, unsigned* __restrict__ m_u,
    int NB, int CAPB, int SRC_BITS, int E)
{
    __shared__ unsigned whist[4][NBMAX];   // 8 KB: per-wave hist, then per-wave cursor
    int tid = threadIdx.x;
    int wv  = tid >> 6;
    for (int i = tid; i < 4 * NBMAX; i += 256) ((unsigned*)whist)[i] = 0;
    __syncthreads();

    int e0 = blockIdx.x * 4096;
    #pragma unroll
    for (int k = 0; k < 16; ++k) {
        int e = e0 + k * 256 + tid;
        if (e < E) atomicAdd(&whist[wv][targets[e] >> BSHIFT], 1u);
    }
    __syncthreads();

    for (int i = tid; i < NB; i += 256) {
        unsigned h0 = whist[0][i], h1 = whist[1][i], h2 = whist[2][i], h3 = whist[3][i];
        unsigned tot = h0 + h1 + h2 + h3;
        if (tot) {
            unsigned g = atomicAdd(gcnt + i, tot);
            whist[0][i] = g;
            whist[1][i] = g + h0;
            whist[2][i] = g + h0 + h1;
            whist[3][i] = g + h0 + h1 + h2;
        }
    }
    __syncthreads();

    #pragma unroll
    for (int k = 0; k < 16; ++k) {
        int e = e0 + k * 256 + tid;
        if (e < E) {
            int tg = targets[e];            // L2/L1-hot from the count pass
            int s  = sources[e];
            int b  = tg >> BSHIFT;
            unsigned pos = atomicAdd(&whist[wv][b], 1u);   // absolute index
            if (pos < (unsigned)CAPB) {
                buf[(size_t)b * CAPB + pos] =
                    ((unsigned)(tg & (BRANGE - 1)) << SRC_BITS) | (unsigned)s;
            } else {
                uint4 tv = t_pk4[s];
                unsigned* mp = m_u + (size_t)tg * HD;
                atomicMax(mp + 0, fmap(bf_lo(tv.x)));
                atomicMax(mp + 1, fmap(bf_hi(tv.x)));
                atomicMax(mp + 2, fmap(bf_lo(tv.y)));
                atomicMax(mp + 3, fmap(bf_hi(tv.y)));
                atomicMax(mp + 4, fmap(bf_lo(tv.z)));
                atomicMax(mp + 5, fmap(bf_hi(tv.z)));
                atomicMax(mp + 6, fmap(bf_lo(tv.w)));
                atomicMax(mp + 7, fmap(bf_hi(tv.w)));
            }
        }
    }
}

// Pass 2: one block per bucket, 512 threads. LDS max-table with PADDED stride 9
// (spreads all 32 banks). Stream the bucket's contiguous records, gather t_pk4[src]
// (L2-resident), LDS atomicMax; coalesced m_pk write. m_u merge is SKIPPED when
// gcnt[b] <= CAPB: positions are unique 0..total-1, so no edge of this bucket can
// have taken the overflow path -> m_u is all -inf for these nodes (saves 12.8 MB).
#define MTS 9
__global__ __launch_bounds__(512) void reduce_kernel(
    const unsigned* __restrict__ gcnt, const unsigned* __restrict__ buf,
    const uint4* __restrict__ t_pk4, const unsigned* __restrict__ m_u,
    uint4* __restrict__ m_pk, int CAPB, int SRC_BITS, int N)
{
    __shared__ unsigned mt[BRANGE * MTS];   // 9.2 KB
    int tid = threadIdx.x;
    int b = blockIdx.x;
    for (int i = tid; i < BRANGE * MTS; i += 512) mt[i] = FMAP_NEG_INF;
    __syncthreads();

    unsigned cnt_raw = gcnt[b];
    bool overflow = cnt_raw > (unsigned)CAPB;
    unsigned cnt = overflow ? (unsigned)CAPB : cnt_raw;
    unsigned srcmask = (1u << SRC_BITS) - 1;
    const unsigned* bb = buf + (size_t)b * CAPB;

    for (unsigned i = tid; i < cnt; i += 512) {
        unsigned rec = bb[i];
        unsigned s  = rec & srcmask;
        unsigned tl = rec >> SRC_BITS;
        uint4 tv = t_pk4[s];
        unsigned* mp = mt + tl * MTS;
        atomicMax(mp + 0, fmap(bf_lo(tv.x)));
        atomicMax(mp + 1, fmap(bf_hi(tv.x)));
        atomicMax(mp + 2, fmap(bf_lo(tv.y)));
        atomicMax(mp + 3, fmap(bf_hi(tv.y)));
        atomicMax(mp + 4, fmap(bf_lo(tv.z)));
        atomicMax(mp + 5, fmap(bf_hi(tv.z)));
        atomicMax(mp + 6, fmap(bf_lo(tv.w)));
        atomicMax(mp + 7, fmap(bf_hi(tv.w)));
    }
    __syncthreads();

    int n0 = b << BSHIFT;
    for (int tl = tid; tl < BRANGE; tl += 512) {
        int n = n0 + tl;
        if (n < N) {
            const unsigned* ms = mt + tl * MTS;
            float v0 = funmap(ms[0]), v1 = funmap(ms[1]);
            float v2 = funmap(ms[2]), v3 = funmap(ms[3]);
            float v4 = funmap(ms[4]), v5 = funmap(ms[5]);
            float v6 = funmap(ms[6]), v7 = funmap(ms[7]);
            if (overflow) {                // rare exact path
                const unsigned* mu = m_u + (size_t)n * HD;
                v0 = fmaxf(v0, funmap(mu[0]));
                v1 = fmaxf(v1, funmap(mu[1]));
                v2 = fmaxf(v2, funmap(mu[2]));
                v3 = fmaxf(v3, funmap(mu[3]));
                v4 = fmaxf(v4, funmap(mu[4]));
                v5 = fmaxf(v5, funmap(mu[5]));
                v6 = fmaxf(v6, funmap(mu[6]));
                v7 = fmaxf(v7, funmap(mu[7]));
            }
            uint4 o;                       // lossless: maxes of bf16 values
            o.x = pack_bf16_rne(v0, v1);
            o.y = pack_bf16_rne(v2, v3);
            o.z = pack_bf16_rne(v4, v5);
            o.w = pack_bf16_rne(v6, v7);
            m_pk[n] = o;
        }
    }
}

// ---- Fallback path (old, proven) kernels: used only if packing/workspace fails ----

__global__ __launch_bounds__(256) void seg_max_kernel(
    const int* __restrict__ sources, const int* __restrict__ targets,
    const uint4* __restrict__ t_pk4, unsigned* __restrict__ m_u, int E)
{
    int e = blockIdx.x * 256 + threadIdx.x;
    if (e >= E) return;
    int s  = __builtin_nontemporal_load(sources + e);
    int tg = __builtin_nontemporal_load(targets + e);
    uint4 tv = t_pk4[s];
    unsigned* mp = m_u + (size_t)tg * HD;
    const uint4* m4 = (const uint4*)mp;
    uint4 c0 = m4[0];
    uint4 c1 = m4[1];
    unsigned f;
    f = fmap(bf_lo(tv.x)); if (f > c0.x) atomicMax(mp + 0, f);
    f = fmap(bf_hi(tv.x)); if (f > c0.y) atomicMax(mp + 1, f);
    f = fmap(bf_lo(tv.y)); if (f > c0.z) atomicMax(mp + 2, f);
    f = fmap(bf_hi(tv.y)); if (f > c0.w) atomicMax(mp + 3, f);
    f = fmap(bf_lo(tv.z)); if (f > c1.x) atomicMax(mp + 4, f);
    f = fmap(bf_hi(tv.z)); if (f > c1.y) atomicMax(mp + 5, f);
    f = fmap(bf_lo(tv.w)); if (f > c1.z) atomicMax(mp + 6, f);
    f = fmap(bf_hi(tv.w)); if (f > c1.w) atomicMax(mp + 7, f);
}

__global__ __launch_bounds__(256) void pack_m_kernel(
    const unsigned* __restrict__ m_u, uint4* __restrict__ m_pk, int N)
{
    int n = blockIdx.x * 256 + threadIdx.x;
    if (n >= N) return;
    const uint4* mu4 = (const uint4*)m_u + (size_t)n * 2;
    uint4 c0 = mu4[0];
    uint4 c1 = mu4[1];
    uint4 o;
    o.x = (__float_as_uint(funmap(c0.x)) >> 16) | (__float_as_uint(funmap(c0.y)) & 0xFFFF0000u);
    o.y = (__float_as_uint(funmap(c0.z)) >> 16) | (__float_as_uint(funmap(c0.w)) & 0xFFFF0000u);
    o.z = (__float_as_uint(funmap(c1.x)) >> 16) | (__float_as_uint(funmap(c1.y)) & 0xFFFF0000u);
    o.w = (__float_as_uint(funmap(c1.z)) >> 16) | (__float_as_uint(funmap(c1.w)) & 0xFFFF0000u);
    m_pk[n] = o;
}

// Phase C: out[e,h] = exp(t[src,h] - m[tgt,h]) * drop_mask[e,h].
// (Reference's s = segment_max(exp(ef-m)) + 1e-9 == 1.0f exactly in fp32.)
// 2 edges/thread for load ILP. Stores are CACHEABLE: with lane-stride 64B per 16B
// store instruction, only L2 can merge the partial-line pattern; NT stores bypassed
// the merge -> WRITE_SIZE 132 MB for a 102 MB payload (round-5 counters). __expf:
// arg in [-2,0], error << bf16 tolerance.
__global__ __launch_bounds__(256) void finalize_kernel(
    const int* __restrict__ sources, const int* __restrict__ targets,
    const uint4* __restrict__ t_pk4, const uint4* __restrict__ m_pk,
    const float* __restrict__ dm, float* __restrict__ out, int E)
{
    int e0 = (blockIdx.x * 256 + threadIdx.x) * 2;
    if (e0 >= E) return;
    bool two = (e0 + 1 < E);

    int s0  = __builtin_nontemporal_load(sources + e0);
    int tg0 = __builtin_nontemporal_load(targets + e0);
    int s1  = two ? __builtin_nontemporal_load(sources + e0 + 1) : s0;
    int tg1 = two ? __builtin_nontemporal_load(targets + e0 + 1) : tg0;

    const vf4* dm4 = (const vf4*)dm;
    vf4 a0 = dm4[(size_t)e0 * 2];
    vf4 a1 = dm4[(size_t)e0 * 2 + 1];
    vf4 b0 = two ? dm4[(size_t)e0 * 2 + 2] : a0;
    vf4 b1 = two ? dm4[(size_t)e0 * 2 + 3] : a1;

    uint4 tv0 = t_pk4[s0];
    uint4 mv0 = m_pk[tg0];
    uint4 tv1 = t_pk4[s1];
    uint4 mv1 = m_pk[tg1];

    vf4 o0, o1, o2, o3;
    o0.x = __expf(bf_lo(tv0.x) - bf_lo(mv0.x)) * a0.x;
    o0.y = __expf(bf_lo(tv0.y) - bf_lo(mv0.y)) * a0.y;
    o0.z = __expf(bf_lo(tv0.z) - bf_lo(mv0.z)) * a0.z;
    o0.w = __expf(bf_lo(tv0.w) - bf_lo(mv0.w)) * a0.w;
    o1.x = __expf(bf_hi(tv0.x) - bf_hi(mv0.x)) * a1.x;
    o1.y = __expf(bf_hi(tv0.y) - bf_hi(mv0.y)) * a1.y;
    o1.z = __expf(bf_hi(tv0.z) - bf_hi(mv0.z)) * a1.z;
    o1.w = __expf(bf_hi(tv0.w) - bf_hi(mv0.w)) * a1.w;
    o2.x = __expf(bf_lo(tv1.x) - bf_lo(mv1.x)) * b0.x;
    o2.y = __expf(bf_lo(tv1.y) - bf_lo(mv1.y)) * b0.y;
    o2.z = __expf(bf_lo(tv1.z) - bf_lo(mv1.z)) * b0.z;
    o2.w = __expf(bf_lo(tv1.w) - bf_lo(mv1.w)) * b0.w;
    o3.x = __expf(bf_hi(tv1.x) - bf_hi(mv1.x)) * b1.x;
    o3.y = __expf(bf_hi(tv1.y) - bf_hi(mv1.y)) * b1.y;
    o3.z = __expf(bf_hi(tv1.z) - bf_hi(mv1.z)) * b1.z;
    o3.w = __expf(bf_hi(tv1.w) - bf_hi(mv1.w)) * b1.w;

    vf4* out4 = (vf4*)out;
    out4[(size_t)e0 * 2]     = o0;
    out4[(size_t)e0 * 2 + 1] = o1;
    if (two) {
        out4[(size_t)e0 * 2 + 2] = o2;
        out4[(size_t)e0 * 2 + 3] = o3;
    }
}

extern "C" void kernel_launch(void* const* d_in, const int* in_sizes, int n_in,
                              void* d_out, int out_size, void* d_ws, size_t ws_size,
                              hipStream_t stream)
{
    const float* X       = (const float*)d_in[0];   // (B,N,H,D) fp32
    const float* Wk      = (const float*)d_in[1];   // (D,H,1)   fp32
    const int*   targets = (const int*)d_in[2];     // (B,E)
    const int*   sources = (const int*)d_in[3];     // (B,E)
    const float* dm      = (const float*)d_in[5];   // (B,E,H)

    int E = in_sizes[2];          // B=1
    int N = in_sizes[4];          // degree is (B,N)

    float* out = (float*)d_out;
    int blocksA = (N + 7) / 8;           // 4 waves/block, 2 nodes/wave
    int blocksF = (E + 511) / 512;       // finalize: 2 edges/thread

    // Binned-path parameters.
    int NB = (N + BRANGE - 1) >> BSHIFT;              // buckets of 256 nodes
    int SRC_BITS = 1;
    while ((1 << SRC_BITS) < N && SRC_BITS < 31) ++SRC_BITS;
    bool packable = (NB <= NBMAX) && (SRC_BITS + BSHIFT <= 32);
    long long capll = ((long long)(E + NB - 1) / (NB > 0 ? NB : 1));
    capll = (capll * 3) / 2;                          // mean * 1.5
    capll = (capll + 255) & ~255LL;
    int CAPB = (int)capll;

    // Workspace layout (bytes): t_pk 16N | m_u 32N | m_pk 16N | gcnt 4N | buf NB*CAPB*4
    size_t needed = (size_t)N * 68 + (size_t)NB * (size_t)CAPB * 4;

    char* w = (char*)d_ws;
    unsigned* t_pk = (unsigned*)w;
    unsigned* m_u  = (unsigned*)(w + (size_t)N * 16);
    uint4*    m_pk = (uint4*)  (w + (size_t)N * 48);

    if (packable && ws_size >= needed) {
        unsigned* gcnt = (unsigned*)(w + (size_t)N * 64);
        unsigned* buf  = (unsigned*)(w + (size_t)N * 68);

        attn_tanh_kernel<<<blocksA, 256, 0, stream>>>(X, Wk, t_pk, (uint2*)m_u, gcnt, NB, N);
        int blocksB = (E + 4095) / 4096;
        bin_kernel<<<blocksB, 256, 0, stream>>>(sources, targets, gcnt, buf,
                                                (const uint4*)t_pk, m_u, NB, CAPB, SRC_BITS, E);
        reduce_kernel<<<NB, 512, 0, stream>>>(gcnt, buf, (const uint4*)t_pk, m_u,
                                              m_pk, CAPB, SRC_BITS, N);
        finalize_kernel<<<blocksF, 256, 0, stream>>>(sources, targets, (const uint4*)t_pk,
                                                     m_pk, dm, out, E);
    } else {
        // Fallback: proven atomicMax path (identical numerics).
        attn_tanh_kernel<<<blocksA, 256, 0, stream>>>(X, Wk, t_pk, (uint2*)m_u, nullptr, 0, N);
        int blocksE = (E + 255) / 256;
        seg_max_kernel<<<blocksE, 256, 0, stream>>>(sources, targets, (const uint4*)t_pk, m_u, E);
        int blocksN = (N + 255) / 256;
        pack_m_kernel<<<blocksN, 256, 0, stream>>>(m_u, m_pk, N);
        finalize_kernel<<<blocksF, 256, 0, stream>>>(sources, targets, (const uint4*)t_pk,
                                                     m_pk, dm, out, E);
    }
}